// Round 7
// baseline (1652.655 us; speedup 1.0000x reference)
//
#include <hip/hip_runtime.h>
#include <math.h>

#define NQ 8
#define BB 32
#define NH 16
#define TT 1024
#define HD 64
#define HH 1024   // NH*HD
#define NBLK 1024
#define PER_TENSOR (BB * NH * TT * HD / 4)       // 8388608 f32x4
// ws layout: [0,256): counters | [256, 256+256K): part | then scales
#define PART_OFF 64       // floats (256 bytes)
#define SCALES_OFF (PART_OFF + NBLK * HD)

typedef float f32x4 __attribute__((ext_vector_type(4)));

// ---------------------------------------------------------------------------
// Single persistent kernel, 1024 co-resident blocks (launch_bounds(256,4)
// guarantees 4 blocks/CU on 256 CUs). Three phases with device-scope
// flag synchronization; circuit bubble hidden under k/v register prefetch.
// ---------------------------------------------------------------------------
__global__ __launch_bounds__(256, 4) void k_fused(
        const f32x4* __restrict__ q4, const f32x4* __restrict__ k4,
        const f32x4* __restrict__ v4,
        const float* __restrict__ W_angles, const float* __restrict__ b_angles,
        const float* __restrict__ q_weights, const float* __restrict__ W_post,
        const float* __restrict__ b_post,
        unsigned* __restrict__ cnt, float* __restrict__ part,
        float* __restrict__ scales, f32x4* __restrict__ out4) {
    const int blk = blockIdx.x;          // 0..1023
    const int tid = threadIdx.x;

    // ---------------- Phase A: q partial sums (512 t-rows per block) -------
    {
        const int bid = blk >> 1, chunk = blk & 1;   // (b*16+h), half
        const int hd4 = tid & 15, tg = tid >> 4;
        const f32x4* base = q4 + (size_t)bid * (TT * HD / 4)
                               + (size_t)chunk * 512 * (HD / 4);
        f32x4 acc = (f32x4)(0.f);
#pragma unroll
        for (int i = 0; i < 32; ++i)
            acc += base[(tg + 16 * i) * (HD / 4) + hd4];
        __shared__ f32x4 red[256];
        red[tid] = acc;
        __syncthreads();
        for (int s = 8; s > 0; s >>= 1) {
            if (tg < s) red[tid] += red[tid + s * 16];
            __syncthreads();
        }
        if (tg == 0) {
            f32x4 r = red[tid];
            float* o = part + (size_t)blk * HD + hd4 * 4;
            o[0] = r.x; o[1] = r.y; o[2] = r.z; o[3] = r.w;
        }
        __threadfence();                 // publish partials device-wide
        __syncthreads();
        if (tid == 0) atomicAdd(&cnt[0], 1u);
    }

    // ------- Prefetch 2 cold units (k and v, within = blk) into regs -------
    f32x4 pfk[4], pfv[4];
    {
        const size_t base = (size_t)blk * 1024;
#pragma unroll
        for (int i = 0; i < 4; ++i) {
            pfk[i] = k4[base + i * 256 + tid];
            pfv[i] = v4[base + i * 256 + tid];
        }
#pragma unroll
        for (int i = 0; i < 4; ++i)
            asm volatile("" :: "v"(pfk[i]), "v"(pfv[i]));  // pin issue point
    }

    // ---------------- Phase B: circuit (wave 0 of blocks 0..31) ------------
    if (blk < BB && tid < 64) {
        const int l = tid;               // lane
        while (__hip_atomic_load(&cnt[0], __ATOMIC_ACQUIRE,
                                 __HIP_MEMORY_SCOPE_AGENT) < NBLK)
            __builtin_amdgcn_s_sleep(2);

        // combine 2 chunks -> summary element (head m, dim l)
        float sm[16];
#pragma unroll
        for (int m = 0; m < 16; ++m) {
            const float* p = part + ((size_t)(blk * NH + m) * 2) * HD + l;
            sm[m] = (p[0] + p[HD]) * (1.0f / (float)TT);
        }

        float ang[NQ];
#pragma unroll
        for (int i = 0; i < NQ; ++i) {
            const float* w = W_angles + i * HH;
            float d = 0.f;
#pragma unroll
            for (int m = 0; m < 16; ++m) d += sm[m] * w[m * 64 + l];
#pragma unroll
            for (int off = 32; off; off >>= 1) d += __shfl_xor(d, off);
            ang[i] = d + b_angles[i];
        }

        // state |00..0>: reg bits = wires 0,1; lane bits = wires 2..7
        float2 amp[4];
        amp[0] = make_float2(l == 0 ? 1.f : 0.f, 0.f);
        amp[1] = amp[2] = amp[3] = make_float2(0.f, 0.f);

        auto cmul_add2 = [](float2 A, float2 v, float2 B, float2 w) {
            float2 r;
            r.x = A.x * v.x - A.y * v.y + B.x * w.x - B.y * w.y;
            r.y = A.x * v.y + A.y * v.x + B.x * w.y + B.y * w.x;
            return r;
        };

        auto gate1q = [&](int wire, float2 M00, float2 M01, float2 M10, float2 M11) {
            if (wire < 2) {
                const int rm = (wire == 0) ? 2 : 1;
#pragma unroll
                for (int r = 0; r < 4; ++r) {
                    if (!(r & rm)) {
                        float2 a0 = amp[r], a1 = amp[r | rm];
                        amp[r]      = cmul_add2(M00, a0, M01, a1);
                        amp[r | rm] = cmul_add2(M10, a0, M11, a1);
                    }
                }
            } else {
                const int m = 1 << (7 - wire);
#pragma unroll
                for (int r = 0; r < 4; ++r) {
                    float2 o;
                    o.x = __shfl_xor(amp[r].x, m);
                    o.y = __shfl_xor(amp[r].y, m);
                    const bool hi = (l & m) != 0;
                    float2 a0 = hi ? o : amp[r];
                    float2 a1 = hi ? amp[r] : o;
                    amp[r] = hi ? cmul_add2(M10, a0, M11, a1)
                                : cmul_add2(M00, a0, M01, a1);
                }
            }
        };

        auto cnot = [&](int c, int t) {
            const bool creg = (c < 2), treg = (t < 2);
            if (creg && treg) {
                if (c == 0) { float2 tmp = amp[2]; amp[2] = amp[3]; amp[3] = tmp; }
                else        { float2 tmp = amp[1]; amp[1] = amp[3]; amp[3] = tmp; }
            } else if (creg && !treg) {
                const int tm = 1 << (7 - t);
#pragma unroll
                for (int r = 0; r < 4; ++r) {
                    float2 o;
                    o.x = __shfl_xor(amp[r].x, tm);
                    o.y = __shfl_xor(amp[r].y, tm);
                    const bool sel = (c == 0) ? ((r & 2) != 0) : ((r & 1) != 0);
                    if (sel) amp[r] = o;
                }
            } else if (!creg && treg) {
                const int cm = 1 << (7 - c);
                const bool ctl = (l & cm) != 0;
                if (t == 0) {
                    float2 a = amp[0], bq = amp[2];
                    amp[0] = ctl ? bq : a;  amp[2] = ctl ? a : bq;
                    float2 cq = amp[1], d = amp[3];
                    amp[1] = ctl ? d : cq;  amp[3] = ctl ? cq : d;
                } else {
                    float2 a = amp[0], bq = amp[1];
                    amp[0] = ctl ? bq : a;  amp[1] = ctl ? a : bq;
                    float2 cq = amp[2], d = amp[3];
                    amp[2] = ctl ? d : cq;  amp[3] = ctl ? cq : d;
                }
            } else {
                const int cm = 1 << (7 - c), tm = 1 << (7 - t);
                const bool ctl = (l & cm) != 0;
#pragma unroll
                for (int r = 0; r < 4; ++r) {
                    float2 o;
                    o.x = __shfl_xor(amp[r].x, tm);
                    o.y = __shfl_xor(amp[r].y, tm);
                    if (ctl) amp[r] = o;
                }
            }
        };

#pragma unroll
        for (int i = 0; i < NQ; ++i) {
            const float c = cosf(0.5f * ang[i]), s = sinf(0.5f * ang[i]);
            gate1q(i, make_float2(c, 0.f), make_float2(-s, 0.f),
                      make_float2(s, 0.f), make_float2(c, 0.f));
        }

#pragma unroll
        for (int lay = 0; lay < 2; ++lay) {
#pragma unroll
            for (int i = 0; i < NQ; ++i) {
                const float phi = q_weights[(lay * NQ + i) * 3 + 0];
                const float th  = q_weights[(lay * NQ + i) * 3 + 1];
                const float om  = q_weights[(lay * NQ + i) * 3 + 2];
                const float c = cosf(0.5f * th), s = sinf(0.5f * th);
                const float apo = -0.5f * (phi + om);
                const float amo =  0.5f * (phi - om);
                float2 M00 = make_float2( c * cosf(apo),  c * sinf(apo));
                float2 M11 = make_float2( c * cosf(apo), -c * sinf(apo));
                float2 M01 = make_float2(-s * cosf(amo), -s * sinf(amo));
                float2 M10 = make_float2( s * cosf(amo), -s * sinf(amo));
                gate1q(i, M00, M01, M10, M11);
            }
            const int r = lay + 1;
#pragma unroll
            for (int i = 0; i < NQ; ++i) cnot(i, (i + r) & 7);
        }

        const float p0 = amp[0].x * amp[0].x + amp[0].y * amp[0].y;
        const float p1 = amp[1].x * amp[1].x + amp[1].y * amp[1].y;
        const float p2 = amp[2].x * amp[2].x + amp[2].y * amp[2].y;
        const float p3 = amp[3].x * amp[3].x + amp[3].y * amp[3].y;
        const float pl = p0 + p1 + p2 + p3;
        float z[NQ];
        z[0] = (p0 + p1) - (p2 + p3);
        z[1] = (p0 + p2) - (p1 + p3);
#pragma unroll
        for (int i = 2; i < NQ; ++i)
            z[i] = ((l >> (7 - i)) & 1) ? -pl : pl;
#pragma unroll
        for (int off = 32; off; off >>= 1)
#pragma unroll
            for (int i = 0; i < NQ; ++i) z[i] += __shfl_xor(z[i], off);

        if (l < NH) {
            float lg = b_post[l];
#pragma unroll
            for (int i = 0; i < NQ; ++i) lg += z[i] * W_post[l * NQ + i];
            const float sc = 1.0f + 0.5f * tanhf(lg);
            __hip_atomic_store(&scales[blk * NH + l], sc, __ATOMIC_RELEASE,
                               __HIP_MEMORY_SCOPE_AGENT);
        }
        __threadfence();
        if (l == 0) atomicAdd(&cnt[1], 1u);
    }

    // ---------------- wait for all scales ----------------------------------
    if (tid == 0) {
        while (__hip_atomic_load(&cnt[1], __ATOMIC_ACQUIRE,
                                 __HIP_MEMORY_SCOPE_AGENT) < BB)
            __builtin_amdgcn_s_sleep(2);
    }
    __syncthreads();

    // ---------------- Phase C: scale & store -------------------------------
    auto loadScale = [&](int within) {
        return __hip_atomic_load(&scales[within >> 4], __ATOMIC_ACQUIRE,
                                 __HIP_MEMORY_SCOPE_AGENT);
    };

    // prefetched k unit (u=8, within=blk)
    {
        const float s = loadScale(blk);
        f32x4* outp = out4 + (size_t)PER_TENSOR + (size_t)blk * 1024;
#pragma unroll
        for (int i = 0; i < 4; ++i) {
            f32x4 x = pfk[i] * s;
            __builtin_nontemporal_store(x, &outp[i * 256 + tid]);
        }
    }
    // prefetched v unit (u=16, within=blk)
    {
        const float s = loadScale(blk);
        f32x4* outp = out4 + (size_t)2 * PER_TENSOR + (size_t)blk * 1024;
#pragma unroll
        for (int i = 0; i < 4; ++i) {
            f32x4 x = pfv[i] * s;
            __builtin_nontemporal_store(x, &outp[i * 256 + tid]);
        }
    }
    // remaining 22 units; u compile-time -> tens/in-pointer fold statically
#pragma unroll
    for (int u = 0; u < 24; ++u) {
        if (u == 8 || u == 16) continue;
        const int g = u * NBLK + blk;
        const int tens = g >> 13;            // 8192 units per tensor
        const int within = g & 8191;
        const float s = loadScale(within);
        const size_t base = (size_t)within * 1024;
        const f32x4* in = (tens == 0) ? q4 : (tens == 1) ? k4 : v4;
        f32x4* outp = out4 + (size_t)tens * PER_TENSOR + base;
#pragma unroll
        for (int i = 0; i < 4; ++i) {
            f32x4 x = in[base + i * 256 + tid] * s;
            __builtin_nontemporal_store(x, &outp[i * 256 + tid]);
        }
    }
}

extern "C" void kernel_launch(void* const* d_in, const int* in_sizes, int n_in,
                              void* d_out, int out_size, void* d_ws, size_t ws_size,
                              hipStream_t stream) {
    const f32x4* q        = (const f32x4*)d_in[0];
    const f32x4* k        = (const f32x4*)d_in[1];
    const f32x4* v        = (const f32x4*)d_in[2];
    const float* W_angles = (const float*)d_in[3];
    const float* b_ang    = (const float*)d_in[4];
    const float* q_w      = (const float*)d_in[5];
    const float* W_post   = (const float*)d_in[6];
    const float* b_post   = (const float*)d_in[7];
    f32x4* out = (f32x4*)d_out;

    unsigned* cnt  = (unsigned*)d_ws;
    float* wsf     = (float*)d_ws;
    float* part    = wsf + PART_OFF;      // 1024*64 floats = 256 KiB
    float* scales  = wsf + SCALES_OFF;    // 512 floats

    hipMemsetAsync(d_ws, 0, 256, stream);   // zero flags each call (captured)
    k_fused<<<NBLK, 256, 0, stream>>>(q, k, v, W_angles, b_ang, q_w,
                                      W_post, b_post, cnt, part, scales, out);
}

// Round 8
// 182.284 us; speedup vs baseline: 9.0664x; 9.0664x over previous
//
#include <hip/hip_runtime.h>
#include <math.h>

#define NQ 8
#define BB 32
#define NH 16
#define TT 1024
#define HD 64
#define HH 1024   // NH*HD
#define NCHUNK 8  // T-chunks per (b,head) in summary pass

typedef float f32x4 __attribute__((ext_vector_type(4)));

// ---------------------------------------------------------------------------
// Kernel 1: partial sums of q over T.
// grid = 512*NCHUNK blocks; block (bid,chunk) reduces 128 t-rows of head bid.
// part[blk][64] holds the 64-dim partial sum (un-normalized).
// Plain cached loads: warms the 256MB Infinity Cache for k_scale's q re-read
// (R7 counters confirmed MALL absorbs q's second read).
// ---------------------------------------------------------------------------
__global__ __launch_bounds__(256) void k_summary(const f32x4* __restrict__ q4,
                                                 float* __restrict__ part) {
    const int blk   = blockIdx.x;        // bid*NCHUNK + chunk
    const int bid   = blk >> 3;
    const int chunk = blk & 7;
    const int t     = threadIdx.x;
    const int hd4   = t & 15;            // 16 f32x4 cover HD=64
    const int tg    = t >> 4;            // 16 t-groups
    const f32x4* base = q4 + (size_t)bid * (TT * (HD / 4))
                           + (size_t)chunk * 128 * (HD / 4);

    f32x4 acc = (f32x4)(0.f);
#pragma unroll
    for (int i = 0; i < 8; ++i) {        // 128 t-rows / 16 groups
        acc += base[(tg + 16 * i) * (HD / 4) + hd4];
    }

    __shared__ f32x4 red[256];
    red[t] = acc;
    __syncthreads();
    for (int s = 8; s > 0; s >>= 1) {
        if (tg < s) red[t] += red[t + s * 16];
        __syncthreads();
    }
    if (tg == 0) {
        f32x4 r = red[t];
        float* out = part + (size_t)blk * HD + hd4 * 4;
        out[0] = r.x; out[1] = r.y; out[2] = r.z; out[3] = r.w;
    }
}

// ---------------------------------------------------------------------------
// Kernel 2: one wave64 per batch, whole 256-amplitude state in registers.
// State index s (bit7..bit0): r = s>>6 (2 reg bits), lane = s&63 (6 lane bits).
// Wire w <-> bit (7-w): wire0 -> reg bit1, wire1 -> reg bit0,
//                       wire w in [2,7] -> lane bit (7-w).
// No __syncthreads, no LDS: gates on lane bits via __shfl_xor.
// ---------------------------------------------------------------------------
__global__ __launch_bounds__(64) void k_circuit(
        const float* __restrict__ part, const float* __restrict__ W_angles,
        const float* __restrict__ b_angles, const float* __restrict__ q_weights,
        const float* __restrict__ W_post, const float* __restrict__ b_post,
        float* __restrict__ scales) {
    const int b = blockIdx.x;
    const int l = threadIdx.x;           // lane 0..63

    // ---- combine partials: summary[h] for h = m*64 + l (m = head index) ----
    float sm[16];
    const float* pb = part + (size_t)b * NH * NCHUNK * HD;
#pragma unroll
    for (int m = 0; m < 16; ++m) {
        const float* p = pb + (size_t)m * NCHUNK * HD + l;
        float s = 0.f;
#pragma unroll
        for (int c = 0; c < NCHUNK; ++c) s += p[c * HD];
        sm[m] = s * (1.0f / (float)TT);
    }

    // ---- angles[i] = dot(summary, W_angles[i,:]) + b_angles[i] ----
    float ang[NQ];
#pragma unroll
    for (int i = 0; i < NQ; ++i) {
        const float* w = W_angles + i * HH;
        float d = 0.f;
#pragma unroll
        for (int m = 0; m < 16; ++m) d += sm[m] * w[m * 64 + l];
#pragma unroll
        for (int off = 32; off; off >>= 1) d += __shfl_xor(d, off);
        ang[i] = d + b_angles[i];
    }

    // ---- state |00..0> ----
    float2 amp[4];
    amp[0] = make_float2(l == 0 ? 1.f : 0.f, 0.f);
    amp[1] = amp[2] = amp[3] = make_float2(0.f, 0.f);

    auto cmul_add2 = [](float2 A, float2 v, float2 B, float2 w) {
        float2 r;
        r.x = A.x * v.x - A.y * v.y + B.x * w.x - B.y * w.y;
        r.y = A.x * v.y + A.y * v.x + B.x * w.y + B.y * w.x;
        return r;
    };

    // wire is a compile-time constant at every call site (unrolled loops)
    auto gate1q = [&](int wire, float2 M00, float2 M01, float2 M10, float2 M11) {
        if (wire < 2) {
            const int rm = (wire == 0) ? 2 : 1;
#pragma unroll
            for (int r = 0; r < 4; ++r) {
                if (!(r & rm)) {
                    float2 a0 = amp[r], a1 = amp[r | rm];
                    amp[r]      = cmul_add2(M00, a0, M01, a1);
                    amp[r | rm] = cmul_add2(M10, a0, M11, a1);
                }
            }
        } else {
            const int m = 1 << (7 - wire);
#pragma unroll
            for (int r = 0; r < 4; ++r) {
                float2 o;
                o.x = __shfl_xor(amp[r].x, m);
                o.y = __shfl_xor(amp[r].y, m);
                const bool hi = (l & m) != 0;
                float2 a0 = hi ? o : amp[r];
                float2 a1 = hi ? amp[r] : o;
                amp[r] = hi ? cmul_add2(M10, a0, M11, a1)
                            : cmul_add2(M00, a0, M01, a1);
            }
        }
    };

    auto cnot = [&](int c, int t) {
        const bool creg = (c < 2), treg = (t < 2);
        if (creg && treg) {
            if (c == 0) { float2 tmp = amp[2]; amp[2] = amp[3]; amp[3] = tmp; }
            else        { float2 tmp = amp[1]; amp[1] = amp[3]; amp[3] = tmp; }
        } else if (creg && !treg) {
            const int tm = 1 << (7 - t);
#pragma unroll
            for (int r = 0; r < 4; ++r) {
                float2 o;
                o.x = __shfl_xor(amp[r].x, tm);
                o.y = __shfl_xor(amp[r].y, tm);
                const bool sel = (c == 0) ? ((r & 2) != 0) : ((r & 1) != 0);
                if (sel) amp[r] = o;  // r, sel compile-time
            }
        } else if (!creg && treg) {
            const int cm = 1 << (7 - c);
            const bool ctl = (l & cm) != 0;
            if (t == 0) {  // swap amp[0]<->amp[2], amp[1]<->amp[3]
                float2 a = amp[0], bq = amp[2];
                amp[0] = ctl ? bq : a;  amp[2] = ctl ? a : bq;
                float2 cq = amp[1], d = amp[3];
                amp[1] = ctl ? d : cq;  amp[3] = ctl ? cq : d;
            } else {       // swap amp[0]<->amp[1], amp[2]<->amp[3]
                float2 a = amp[0], bq = amp[1];
                amp[0] = ctl ? bq : a;  amp[1] = ctl ? a : bq;
                float2 cq = amp[2], d = amp[3];
                amp[2] = ctl ? d : cq;  amp[3] = ctl ? cq : d;
            }
        } else {
            const int cm = 1 << (7 - c), tm = 1 << (7 - t);
            const bool ctl = (l & cm) != 0;
#pragma unroll
            for (int r = 0; r < 4; ++r) {
                float2 o;
                o.x = __shfl_xor(amp[r].x, tm);
                o.y = __shfl_xor(amp[r].y, tm);
                if (ctl) amp[r] = o;
            }
        }
    };

    // ---- AngleEmbedding: RY(ang[i]) on wire i ----
#pragma unroll
    for (int i = 0; i < NQ; ++i) {
        const float c = cosf(0.5f * ang[i]), s = sinf(0.5f * ang[i]);
        gate1q(i, make_float2(c, 0.f), make_float2(-s, 0.f),
                  make_float2(s, 0.f), make_float2(c, 0.f));
    }

    // ---- StronglyEntanglingLayers ----
#pragma unroll
    for (int lay = 0; lay < 2; ++lay) {
#pragma unroll
        for (int i = 0; i < NQ; ++i) {
            const float phi = q_weights[(lay * NQ + i) * 3 + 0];
            const float th  = q_weights[(lay * NQ + i) * 3 + 1];
            const float om  = q_weights[(lay * NQ + i) * 3 + 2];
            const float c = cosf(0.5f * th), s = sinf(0.5f * th);
            const float apo = -0.5f * (phi + om);
            const float amo =  0.5f * (phi - om);
            // Rot = RZ(om) RY(th) RZ(phi)
            float2 M00 = make_float2( c * cosf(apo),  c * sinf(apo));
            float2 M11 = make_float2( c * cosf(apo), -c * sinf(apo));
            float2 M01 = make_float2(-s * cosf(amo), -s * sinf(amo));
            float2 M10 = make_float2( s * cosf(amo), -s * sinf(amo));
            gate1q(i, M00, M01, M10, M11);
        }
        const int r = lay + 1;   // (lay % (NQ-1)) + 1
#pragma unroll
        for (int i = 0; i < NQ; ++i) cnot(i, (i + r) & 7);
    }

    // ---- expvals <Z_i> ----
    const float p0 = amp[0].x * amp[0].x + amp[0].y * amp[0].y;
    const float p1 = amp[1].x * amp[1].x + amp[1].y * amp[1].y;
    const float p2 = amp[2].x * amp[2].x + amp[2].y * amp[2].y;
    const float p3 = amp[3].x * amp[3].x + amp[3].y * amp[3].y;
    const float pl = p0 + p1 + p2 + p3;
    float z[NQ];
    z[0] = (p0 + p1) - (p2 + p3);   // reg bit1 (wire 0)
    z[1] = (p0 + p2) - (p1 + p3);   // reg bit0 (wire 1)
#pragma unroll
    for (int i = 2; i < NQ; ++i)
        z[i] = ((l >> (7 - i)) & 1) ? -pl : pl;
#pragma unroll
    for (int off = 32; off; off >>= 1)
#pragma unroll
        for (int i = 0; i < NQ; ++i) z[i] += __shfl_xor(z[i], off);

    // ---- head logits -> scales ----
    if (l < NH) {
        float lg = b_post[l];
#pragma unroll
        for (int i = 0; i < NQ; ++i) lg += z[i] * W_post[l * NQ + i];
        scales[b * NH + l] = 1.0f + 0.5f * tanhf(lg);
    }
}

// ---------------------------------------------------------------------------
// Kernel 3: out = concat(q*sb, k*sb, v*sb).
// grid = (8192, 3): y selects tensor, x selects 1024-float4 block (16/head).
// Measured-best cache modes: PLAIN loads (R6 183.0 vs R3 nt-loads 187.7),
// NT stores (R5 plain stores 197.0). q re-read rides the Infinity Cache.
// ---------------------------------------------------------------------------
__global__ __launch_bounds__(256) void k_scale(
        const f32x4* __restrict__ q4, const f32x4* __restrict__ k4,
        const f32x4* __restrict__ v4, const float* __restrict__ scales,
        f32x4* __restrict__ out4) {
    const int  perTensor = BB * NH * TT * HD / 4;   // 8388608 f32x4
    const int  tens = blockIdx.y;
    const int  blk  = blockIdx.x;                   // 0..8191
    const int  t    = threadIdx.x;
    const float s   = scales[blk >> 4];             // 16 blocks per head

    const f32x4* in = (tens == 0) ? q4 : (tens == 1) ? k4 : v4;
    const size_t base = (size_t)blk * 1024;
    const f32x4* inp  = in + base;
    f32x4*       outp = out4 + (size_t)tens * perTensor + base;

#pragma unroll
    for (int i = 0; i < 4; ++i) {
        const int idx = i * 256 + t;
        f32x4 x = inp[idx];         // plain cached load for q, k, and v
        x *= s;
        __builtin_nontemporal_store(x, &outp[idx]);
    }
}

extern "C" void kernel_launch(void* const* d_in, const int* in_sizes, int n_in,
                              void* d_out, int out_size, void* d_ws, size_t ws_size,
                              hipStream_t stream) {
    const float* q        = (const float*)d_in[0];
    const float* k        = (const float*)d_in[1];
    const float* v        = (const float*)d_in[2];
    const float* W_angles = (const float*)d_in[3];
    const float* b_ang    = (const float*)d_in[4];
    const float* q_w      = (const float*)d_in[5];
    const float* W_post   = (const float*)d_in[6];
    const float* b_post   = (const float*)d_in[7];
    float* out = (float*)d_out;

    float* part   = (float*)d_ws;                          // 4096*64 floats = 1 MiB
    float* scales = part + (size_t)BB * NH * NCHUNK * HD;  // 512 floats

    k_summary<<<BB * NH * NCHUNK, 256, 0, stream>>>((const f32x4*)q, part);
    k_circuit<<<BB, 64, 0, stream>>>(part, W_angles, b_ang, q_w,
                                     W_post, b_post, scales);
    dim3 grid(8192, 3);
    k_scale<<<grid, 256, 0, stream>>>((const f32x4*)q, (const f32x4*)k,
                                      (const f32x4*)v, scales, (f32x4*)out);
}